// Round 17
// baseline (9119.401 us; speedup 1.0000x reference)
//
#include <hip/hip_runtime.h>
#include <hip/hip_bf16.h>

#pragma clang fp contract(off)

#define NTH   1024      // 16 waves, 1 block per CU
#define PPT   16        // NTH*PPT == NPTS
#define NPTS  16384
#define BATCH 16
#define CFEAT 128
#define SMAX  4096
#define NWAVE (NTH / 64)
// Prune margin (r15-proven exact): skip iff lb*PRUNE_C >= waveMaxD.
#define PRUNE_C 0.999995f

__device__ __forceinline__ unsigned spread3(unsigned v) {
    v &= 0x3FFu;
    v = (v | (v << 16)) & 0x030000FFu;
    v = (v | (v << 8))  & 0x0300F00Fu;
    v = (v | (v << 4))  & 0x030C30C3u;
    v = (v | (v << 2))  & 0x09249249u;
    return v;
}
__device__ __forceinline__ unsigned qz10(float v) {
    int q = (int)((v + 6.0f) * (1023.0f / 12.0f));   // layout-only
    q = q < 0 ? 0 : (q > 1023 ? 1023 : q);
    return (unsigned)q;
}
__device__ __forceinline__ unsigned morton30(float x, float y, float z) {
    return (spread3(qz10(x)) << 2) | (spread3(qz10(y)) << 1) | spread3(qz10(z));
}

// ---------------------------------------------------------------------------
// FPS kernel, one block per batch.
// CORRECTNESS INVARIANTS (proven r0-r16; do not change):
//   * d  = fma(dz,dz, fma(dx,dx, dy*dy))   [XLA contraction form]
//   * md = fminf(D[k], d)
//   * argmax: max value, ties -> LOWEST ORIGINAL point index
//   * emission: idx[t] = last BEFORE the update pass
// r17 machinery:
//   * counting sort (256 morton buckets) replaces bitonic: layout-only, ~40us
//     vs ~500us. Within-bucket order arbitrary-but-unique; output invariant
//     because prune-skips are bitwise no-ops (r15 margin proof) and the
//     argmax total order uses ORIGINAL indices only.
//   * per-thread u64 pack (mdbits<<32 | ~origidx) + coords tracked ONLINE in
//     the update loop (static selects). Total order exact; ties impossible
//     (origidx unique).
//   * wave winner via u64 DPP butterfly (r13-proven DPP ctrl sequence);
//     unique owning lane publishes {pk,x,y,z} to a PERSISTENT double-buffered
//     per-wave slot. Skipped waves: lane0 copies slot across parity (D
//     unchanged => pack+coords still valid). ONE barrier, no atomics.
//   * post-barrier: serial 16-slot scan (r12 shape); winner coords read from
//     the slot -> no global coord fetch on the critical path.
// ---------------------------------------------------------------------------
template <bool FUSED>
__global__ __launch_bounds__(NTH) void fps_kernel(const float* __restrict__ xyz,
                                                  const float* __restrict__ x,
                                                  int* __restrict__ idx_out,
                                                  float* __restrict__ out,
                                                  int S) {
    const int b    = blockIdx.x;
    const int tid  = threadIdx.x;
    const int wid  = tid >> 6;
    const int lane = tid & 63;
    const float* __restrict__ xb = xyz + (size_t)b * 3 * NPTS;

    __shared__ unsigned s_ord[NPTS];            // 64 KB: sorted pos -> orig idx
    __shared__ unsigned s_hist[256];
    __shared__ unsigned long long s_pk[2][NWAVE];
    __shared__ float    s_cx[2][NWAVE], s_cy[2][NWAVE], s_cz[2][NWAVE];
    __shared__ int      s_idx[FUSED ? SMAX : 1];

    // ---- phase 0a: bucket histogram
    for (int i = tid; i < 256; i += NTH) s_hist[i] = 0;
    __syncthreads();
    for (int k = 0; k < PPT; ++k) {
        const int p = k * NTH + tid;
        const unsigned m = morton30(xb[p], xb[NPTS + p], xb[2 * NPTS + p]);
        atomicAdd(&s_hist[m >> 22], 1u);
    }
    __syncthreads();
    // ---- phase 0b: exclusive prefix (serial, one-time)
    if (tid == 0) {
        unsigned acc = 0;
        for (int i = 0; i < 256; ++i) { const unsigned c = s_hist[i]; s_hist[i] = acc; acc += c; }
    }
    __syncthreads();
    // ---- phase 0c: scatter orig indices to sorted order
    for (int k = 0; k < PPT; ++k) {
        const int p = k * NTH + tid;
        const unsigned m = morton30(xb[p], xb[NPTS + p], xb[2 * NPTS + p]);
        const unsigned pos = atomicAdd(&s_hist[m >> 22], 1u);
        s_ord[pos] = (unsigned)p;
    }
    __syncthreads();

    // ---- phase 0d: wave-chunk gather (coalesced s_ord reads) + wave bbox
    // Wave wid owns sorted positions [wid*1024, wid*1024+1024); thread's 16
    // points are lane-strided within the chunk (bbox is per-WAVE, so thread-
    // level layout is free; tie-break uses explicit orig indices).
    float X[PPT], Y[PPT], Z[PPT], D[PPT];
    unsigned VI[PPT / 2];
    float bxl =  INFINITY, byl =  INFINITY, bzl =  INFINITY;
    float bxh = -INFINITY, byh = -INFINITY, bzh = -INFINITY;
#pragma unroll
    for (int k = 0; k < PPT; ++k) {
        const unsigned gi = s_ord[wid * (64 * PPT) + k * 64 + lane];
        const float xx = xb[gi], yy = xb[NPTS + gi], zz = xb[2 * NPTS + gi];
        X[k] = xx; Y[k] = yy; Z[k] = zz; D[k] = INFINITY;
        if ((k & 1) == 0) VI[k >> 1] = gi;
        else              VI[k >> 1] |= (gi << 16);
        bxl = fminf(bxl, xx); bxh = fmaxf(bxh, xx);
        byl = fminf(byl, yy); byh = fmaxf(byh, yy);
        bzl = fminf(bzl, zz); bzh = fmaxf(bzh, zz);
    }
#pragma unroll
    for (int off = 32; off >= 1; off >>= 1) {
        bxl = fminf(bxl, __shfl_xor(bxl, off)); bxh = fmaxf(bxh, __shfl_xor(bxh, off));
        byl = fminf(byl, __shfl_xor(byl, off)); byh = fmaxf(byh, __shfl_xor(byh, off));
        bzl = fminf(bzl, __shfl_xor(bzl, off)); bzh = fmaxf(bzh, __shfl_xor(bzh, off));
    }

    int   last  = 0;
    float px = xb[0], py = xb[NPTS], pz = xb[2 * NPTS];
    float wBest = INFINITY;   // cached wave max (uniform; valid across skips)

    for (int t = 0; t < S; ++t) {
        if (tid == 0) {
            if (FUSED) s_idx[t] = last;
            else       idx_out[b * S + t] = last;
        }
        const int buf = t & 1;

        // ---- wave-level prune test (uniform operands)
        const float gx = fmaxf(fmaxf(bxl - px, px - bxh), 0.0f);
        const float gy = fmaxf(fmaxf(byl - py, py - byh), 0.0f);
        const float gz = fmaxf(fmaxf(bzl - pz, pz - bzh), 0.0f);
        const float lb = gx * gx + gy * gy + gz * gz;

        if (!(lb * PRUNE_C >= wBest)) {
            // ---- update + online pack/coord tracking (all-static selects)
            unsigned phi = 0, plo = 0;            // thread-best pack
            float cx = 0.f, cy = 0.f, cz = 0.f;
#pragma unroll
            for (int k = 0; k < PPT; ++k) {
                const float dx = X[k] - px, dy = Y[k] - py, dz = Z[k] - pz;
                const float d  = __builtin_fmaf(dz, dz, __builtin_fmaf(dx, dx, dy * dy));
                const float md = fminf(D[k], d);
                D[k] = md;
                const unsigned gg = (VI[k >> 1] >> ((k & 1) * 16)) & 0xFFFFu;
                const unsigned hi = __float_as_uint(md);
                const unsigned lo = ~gg;
                if (hi > phi || (hi == phi && lo > plo)) {
                    phi = hi; plo = lo; cx = X[k]; cy = Y[k]; cz = Z[k];
                }
            }
            // ---- wave u64 pack max via DPP (r13-proven ctrl sequence)
            unsigned rhi = phi, rlo = plo;
#define DPP_PKMAX(CTRL)                                                        \
            {                                                                  \
                const unsigned nlo = (unsigned)__builtin_amdgcn_update_dpp(    \
                    0, (int)rlo, (CTRL), 0xf, 0xf, true);                      \
                const unsigned nhi = (unsigned)__builtin_amdgcn_update_dpp(    \
                    0, (int)rhi, (CTRL), 0xf, 0xf, true);                      \
                if (nhi > rhi || (nhi == rhi && nlo > rlo)) { rhi = nhi; rlo = nlo; } \
            }
            DPP_PKMAX(0x111)   // row_shr:1
            DPP_PKMAX(0x112)   // row_shr:2
            DPP_PKMAX(0x114)   // row_shr:4
            DPP_PKMAX(0x118)   // row_shr:8
            DPP_PKMAX(0x142)   // row_bcast:15
            DPP_PKMAX(0x143)   // row_bcast:31
#undef DPP_PKMAX
            const unsigned whi = (unsigned)__builtin_amdgcn_readlane((int)rhi, 63);
            const unsigned wlo = (unsigned)__builtin_amdgcn_readlane((int)rlo, 63);
            wBest = __uint_as_float(whi);

            // unique owning lane publishes pack + coords
            if (phi == whi && plo == wlo) {
                s_pk[buf][wid] = ((unsigned long long)whi << 32) | wlo;
                s_cx[buf][wid] = cx;
                s_cy[buf][wid] = cy;
                s_cz[buf][wid] = cz;
            }
        } else {
            // skipped: slot content unchanged -> copy across buffer parity
            if (lane == 0) {
                s_pk[buf][wid] = s_pk[buf ^ 1][wid];
                s_cx[buf][wid] = s_cx[buf ^ 1][wid];
                s_cy[buf][wid] = s_cy[buf ^ 1][wid];
                s_cz[buf][wid] = s_cz[buf ^ 1][wid];
            }
        }
        __syncthreads();                       // the ONE barrier

        // ---- all threads: serial 16-slot scan (r12 shape)
        unsigned long long win = s_pk[buf][0];
        int w = 0;
#pragma unroll
        for (int w2 = 1; w2 < NWAVE; ++w2) {
            const unsigned long long pw = s_pk[buf][w2];
            if (pw > win) { win = pw; w = w2; }
        }
        last = (int)(~(unsigned)(win & 0xFFFFFFFFull));   // ~(~gg) = gg (14-bit)
        px = s_cx[buf][w];
        py = s_cy[buf][w];
        pz = s_cz[buf][w];
    }

    if (FUSED) {
        __syncthreads();
        for (int i = tid; i < CFEAT * S; i += NTH) {
            const int c = i / S, s = i - c * S;
            const long r = (long)b * CFEAT + c;
            out[r * S + s] = x[r * NPTS + s_idx[s]];
        }
        const long base2 = (long)BATCH * CFEAT * S;
        for (int i = tid; i < 3 * S; i += NTH) {
            const int c = i / S, s = i - c * S;
            const long r = (long)b * 3 + c;
            out[base2 + r * S + s] = xyz[r * NPTS + s_idx[s]];
        }
    }
}

// ---------------------------------------------------------------------------
// Gather kernel (full-chip): out = concat( x_s [B][C][S], xyz_s [B][3][S] ).
// ---------------------------------------------------------------------------
__global__ void gather_kernel(const float* __restrict__ x,
                              const float* __restrict__ xyz,
                              const int* __restrict__ idx,
                              float* __restrict__ out,
                              int S) {
    const long nxs   = (long)BATCH * CFEAT * S;
    const long total = nxs + (long)BATCH * 3 * S;
    for (long i = (long)blockIdx.x * blockDim.x + threadIdx.x; i < total;
         i += (long)gridDim.x * blockDim.x) {
        if (i < nxs) {
            const int s  = (int)(i % S);
            const long r = i / S;            // b*C + c
            const int b  = (int)(r / CFEAT);
            const int p  = idx[b * S + s];
            out[i] = x[r * NPTS + p];
        } else {
            const long j = i - nxs;
            const int s  = (int)(j % S);
            const long r = j / S;            // b*3 + c
            const int b  = (int)(r / 3);
            const int p  = idx[b * S + s];
            out[i] = xyz[r * NPTS + p];
        }
    }
}

extern "C" void kernel_launch(void* const* d_in, const int* in_sizes, int n_in,
                              void* d_out, int out_size, void* d_ws, size_t ws_size,
                              hipStream_t stream) {
    const float* x   = nullptr;   // [B, C, N]
    const float* xyz = nullptr;   // [B, 3, N]
    for (int i = 0; i < n_in; ++i) {
        if (in_sizes[i] == BATCH * CFEAT * NPTS)  x   = (const float*)d_in[i];
        else if (in_sizes[i] == BATCH * 3 * NPTS) xyz = (const float*)d_in[i];
    }
    float* out = (float*)d_out;
    const int S = out_size / (BATCH * (CFEAT + 3));

    const size_t need = (size_t)BATCH * (size_t)S * sizeof(int);
    if (ws_size >= need && d_ws != nullptr) {
        int* idx = (int*)d_ws;
        fps_kernel<false><<<BATCH, NTH, 0, stream>>>(xyz, nullptr, idx, nullptr, S);
        gather_kernel<<<2048, 256, 0, stream>>>(x, xyz, idx, out, S);
    } else {
        fps_kernel<true><<<BATCH, NTH, 0, stream>>>(xyz, x, nullptr, out, S);
    }
}

// Round 18
// 4490.583 us; speedup vs baseline: 2.0308x; 2.0308x over previous
//
#include <hip/hip_runtime.h>
#include <hip/hip_bf16.h>

#pragma clang fp contract(off)

#define NTH   1024      // 16 waves, 1 block per CU
#define PPT   16        // NTH*PPT == NPTS
#define NPTS  16384
#define BATCH 16
#define CFEAT 128
#define SMAX  4096
#define NWAVE (NTH / 64)
// Prune margin (r15-proven exact): skip iff lb*PRUNE_C >= waveMaxD.
#define PRUNE_C 0.999995f

__device__ __forceinline__ unsigned spread3(unsigned v) {
    v &= 0x3FFu;
    v = (v | (v << 16)) & 0x030000FFu;
    v = (v | (v << 8))  & 0x0300F00Fu;
    v = (v | (v << 4))  & 0x030C30C3u;
    v = (v | (v << 2))  & 0x09249249u;
    return v;
}
__device__ __forceinline__ unsigned qz10(float v) {
    int q = (int)((v + 6.0f) * (1023.0f / 12.0f));   // layout-only
    q = q < 0 ? 0 : (q > 1023 ? 1023 : q);
    return (unsigned)q;
}
__device__ __forceinline__ unsigned morton30(float x, float y, float z) {
    return (spread3(qz10(x)) << 2) | (spread3(qz10(y)) << 1) | spread3(qz10(z));
}

// ---------------------------------------------------------------------------
// FPS kernel, one block per batch.
// CORRECTNESS INVARIANTS (proven r0-r17; do not change):
//   * d  = fma(dz,dz, fma(dx,dx, dy*dy))   [XLA contraction form]
//   * md = fminf(D[k], d)
//   * argmax: max value, ties -> LOWEST ORIGINAL point index
//   * emission: idx[t] = last BEFORE the update pass
// r18 machinery (r16 loop + three tail cuts):
//   * counting sort (r17-proven, ~100us, conflict-light) for morton layout.
//   * idx emitted to LDS s_idx ALWAYS; dumped to global after the loop.
//     Removes the loop's only global STORE -> the compiler's vmcnt(0) drain
//     before s_barrier no longer waits on store completion each iteration.
//   * DPP u32 value butterfly (r13-proven ctrl sequence, ~60cyc) replaces
//     the 6-chained ds_bpermute shuffle (~210cyc) for the wave max.
//   * rest is r16 verbatim: value-only update (8 VALU/pt), rare candidate
//     rescan (gg only), atomicMax u64 rotating cell (pack = mdbits<<32 |
//     (0xFFFFFFFF-origidx): integer max == frozen total order), distance-2
//     rotate-init, uniform global coord fetch (L2), wave bbox pruning.
// ---------------------------------------------------------------------------
template <bool FUSED>
__global__ __launch_bounds__(NTH) void fps_kernel(const float* __restrict__ xyz,
                                                  const float* __restrict__ x,
                                                  int* __restrict__ idx_out,
                                                  float* __restrict__ out,
                                                  int S) {
    const int b    = blockIdx.x;
    const int tid  = threadIdx.x;
    const int wid  = tid >> 6;
    const int lane = tid & 63;
    const float* __restrict__ xb = xyz + (size_t)b * 3 * NPTS;

    __shared__ unsigned s_ord[NPTS];            // 64 KB: sorted pos -> orig idx
    __shared__ unsigned s_hist[256];
    __shared__ unsigned long long s_slot[4];
    __shared__ int s_idx[SMAX];                 // idx ring (always LDS)

    // ---- phase 0a: bucket histogram
    for (int i = tid; i < 256; i += NTH) s_hist[i] = 0;
    __syncthreads();
    for (int k = 0; k < PPT; ++k) {
        const int p = k * NTH + tid;
        const unsigned m = morton30(xb[p], xb[NPTS + p], xb[2 * NPTS + p]);
        atomicAdd(&s_hist[m >> 22], 1u);
    }
    __syncthreads();
    // ---- phase 0b: exclusive prefix (serial, one-time)
    if (tid == 0) {
        unsigned acc = 0;
        for (int i = 0; i < 256; ++i) { const unsigned c = s_hist[i]; s_hist[i] = acc; acc += c; }
    }
    __syncthreads();
    // ---- phase 0c: scatter orig indices to sorted order
    for (int k = 0; k < PPT; ++k) {
        const int p = k * NTH + tid;
        const unsigned m = morton30(xb[p], xb[NPTS + p], xb[2 * NPTS + p]);
        const unsigned pos = atomicAdd(&s_hist[m >> 22], 1u);
        s_ord[pos] = (unsigned)p;
    }
    if (tid == 0) { s_slot[0] = s_slot[1] = s_slot[2] = s_slot[3] = 0ull; }
    __syncthreads();

    // ---- phase 0d: wave-chunk gather + wave bbox (r17-proven layout)
    float X[PPT], Y[PPT], Z[PPT], D[PPT];
    unsigned VI[PPT / 2];
    float bxl =  INFINITY, byl =  INFINITY, bzl =  INFINITY;
    float bxh = -INFINITY, byh = -INFINITY, bzh = -INFINITY;
#pragma unroll
    for (int k = 0; k < PPT; ++k) {
        const unsigned gi = s_ord[wid * (64 * PPT) + k * 64 + lane];
        const float xx = xb[gi], yy = xb[NPTS + gi], zz = xb[2 * NPTS + gi];
        X[k] = xx; Y[k] = yy; Z[k] = zz; D[k] = INFINITY;
        if ((k & 1) == 0) VI[k >> 1] = gi;
        else              VI[k >> 1] |= (gi << 16);
        bxl = fminf(bxl, xx); bxh = fmaxf(bxh, xx);
        byl = fminf(byl, yy); byh = fmaxf(byh, yy);
        bzl = fminf(bzl, zz); bzh = fmaxf(bzh, zz);
    }
#pragma unroll
    for (int off = 32; off >= 1; off >>= 1) {
        bxl = fminf(bxl, __shfl_xor(bxl, off)); bxh = fmaxf(bxh, __shfl_xor(bxh, off));
        byl = fminf(byl, __shfl_xor(byl, off)); byh = fmaxf(byh, __shfl_xor(byh, off));
        bzl = fminf(bzl, __shfl_xor(bzl, off)); bzh = fmaxf(bzh, __shfl_xor(bzh, off));
    }

    int   last  = 0;
    float px = xb[0], py = xb[NPTS], pz = xb[2 * NPTS];
    float wBest = INFINITY;           // cached wave max (valid across skips)
    unsigned long long myPack = 0;    // cached candidate pack (per lane)

    for (int t = 0; t < S; ++t) {
        if (tid == 0) s_idx[t] = last;          // LDS only - no global store

        // ---- wave-level prune test (uniform operands)
        const float gx = fmaxf(fmaxf(bxl - px, px - bxh), 0.0f);
        const float gy = fmaxf(fmaxf(byl - py, py - byh), 0.0f);
        const float gz = fmaxf(fmaxf(bzl - pz, pz - bzh), 0.0f);
        const float lb = gx * gx + gy * gy + gz * gz;

        if (!(lb * PRUNE_C >= wBest)) {
            // ---- value-only update (8 VALU/pt)
            float bestv = -INFINITY;
#pragma unroll
            for (int k = 0; k < PPT; ++k) {
                const float dx = X[k] - px, dy = Y[k] - py, dz = Z[k] - pz;
                const float d  = __builtin_fmaf(dz, dz, __builtin_fmaf(dx, dx, dy * dy));
                const float md = fminf(D[k], d);
                D[k] = md;
                bestv = fmaxf(bestv, md);
            }
            const unsigned mybits = __float_as_uint(bestv);

            // ---- wave max via DPP (r13-proven ctrl sequence)
            unsigned red = mybits;
#define DPP_MAX_STEP(CTRL)                                                     \
            {                                                                  \
                const unsigned tpp = (unsigned)__builtin_amdgcn_update_dpp(    \
                    0, (int)red, (CTRL), 0xf, 0xf, true);                      \
                red = (tpp > red) ? tpp : red;                                 \
            }
            DPP_MAX_STEP(0x111)   // row_shr:1
            DPP_MAX_STEP(0x112)   // row_shr:2
            DPP_MAX_STEP(0x114)   // row_shr:4
            DPP_MAX_STEP(0x118)   // row_shr:8
            DPP_MAX_STEP(0x142)   // row_bcast:15
            DPP_MAX_STEP(0x143)   // row_bcast:31
#undef DPP_MAX_STEP
            const unsigned bu = (unsigned)__builtin_amdgcn_readlane((int)red, 63);
            wBest = __uint_as_float(bu);

            myPack = 0;
            if (mybits == bu) {               // candidate lane(s), ~1 per wave
                unsigned mo = 0xFFFFFFFFu;    // lowest ORIGINAL idx at max
#pragma unroll
                for (int k = 0; k < PPT; ++k) {
                    if (__float_as_uint(D[k]) == mybits) {
                        const unsigned gg = (VI[k >> 1] >> ((k & 1) * 16)) & 0xFFFFu;
                        mo = (gg < mo) ? gg : mo;
                    }
                }
                myPack = ((unsigned long long)mybits << 32)
                       | (unsigned long long)(0xFFFFFFFFu - mo);
            }
        }
        // candidates (fresh or cached from skipped iterations) publish
        if (myPack) atomicMax(&s_slot[t & 3], myPack);
        if (tid == 0) s_slot[(t + 2) & 3] = 0ull;      // distance-2 rotate-init
        __syncthreads();                                // the ONE barrier

        const unsigned long long win = s_slot[t & 3];
        last = (int)(0xFFFFFFFFu - (unsigned)(win & 0xFFFFFFFFull));
        px = xb[last]; py = xb[NPTS + last]; pz = xb[2 * NPTS + last];
    }

    __syncthreads();
    if (!FUSED) {
        // dump idx ring to global (coalesced, once)
        for (int i = tid; i < S; i += NTH) idx_out[b * S + i] = s_idx[i];
    } else {
        for (int i = tid; i < CFEAT * S; i += NTH) {
            const int c = i / S, s = i - c * S;
            const long r = (long)b * CFEAT + c;
            out[r * S + s] = x[r * NPTS + s_idx[s]];
        }
        const long base2 = (long)BATCH * CFEAT * S;
        for (int i = tid; i < 3 * S; i += NTH) {
            const int c = i / S, s = i - c * S;
            const long r = (long)b * 3 + c;
            out[base2 + r * S + s] = xyz[r * NPTS + s_idx[s]];
        }
    }
}

// ---------------------------------------------------------------------------
// Gather kernel (full-chip): out = concat( x_s [B][C][S], xyz_s [B][3][S] ).
// ---------------------------------------------------------------------------
__global__ void gather_kernel(const float* __restrict__ x,
                              const float* __restrict__ xyz,
                              const int* __restrict__ idx,
                              float* __restrict__ out,
                              int S) {
    const long nxs   = (long)BATCH * CFEAT * S;
    const long total = nxs + (long)BATCH * 3 * S;
    for (long i = (long)blockIdx.x * blockDim.x + threadIdx.x; i < total;
         i += (long)gridDim.x * blockDim.x) {
        if (i < nxs) {
            const int s  = (int)(i % S);
            const long r = i / S;            // b*C + c
            const int b  = (int)(r / CFEAT);
            const int p  = idx[b * S + s];
            out[i] = x[r * NPTS + p];
        } else {
            const long j = i - nxs;
            const int s  = (int)(j % S);
            const long r = j / S;            // b*3 + c
            const int b  = (int)(r / 3);
            const int p  = idx[b * S + s];
            out[i] = xyz[r * NPTS + p];
        }
    }
}

extern "C" void kernel_launch(void* const* d_in, const int* in_sizes, int n_in,
                              void* d_out, int out_size, void* d_ws, size_t ws_size,
                              hipStream_t stream) {
    const float* x   = nullptr;   // [B, C, N]
    const float* xyz = nullptr;   // [B, 3, N]
    for (int i = 0; i < n_in; ++i) {
        if (in_sizes[i] == BATCH * CFEAT * NPTS)  x   = (const float*)d_in[i];
        else if (in_sizes[i] == BATCH * 3 * NPTS) xyz = (const float*)d_in[i];
    }
    float* out = (float*)d_out;
    const int S = out_size / (BATCH * (CFEAT + 3));

    const size_t need = (size_t)BATCH * (size_t)S * sizeof(int);
    if (ws_size >= need && d_ws != nullptr) {
        int* idx = (int*)d_ws;
        fps_kernel<false><<<BATCH, NTH, 0, stream>>>(xyz, nullptr, idx, nullptr, S);
        gather_kernel<<<2048, 256, 0, stream>>>(x, xyz, idx, out, S);
    } else {
        fps_kernel<true><<<BATCH, NTH, 0, stream>>>(xyz, x, nullptr, out, S);
    }
}